// Round 9
// baseline (421.607 us; speedup 1.0000x reference)
//
#include <hip/hip_runtime.h>

// B=16, L=2048, K=24, D=64
typedef _Float16 f16;
typedef _Float16 f16x4 __attribute__((ext_vector_type(4)));
typedef _Float16 f16x8 __attribute__((ext_vector_type(8)));
typedef float f32x4 __attribute__((ext_vector_type(4)));

__device__ __forceinline__ void gl_lds16(const void* g, void* l) {
  __builtin_amdgcn_global_load_lds(
      (__attribute__((address_space(1))) unsigned int*)(g),
      (__attribute__((address_space(3))) unsigned int*)(l), 16, 0, 0);
}

// ---- k_pre: fused precompute.
// blocks 0..383:   Apre[diag][k][t][s] = lam_k^(1/4) * evec[diag*128+t-s][k]
// blocks 384..407: phiT[k][e][d] = (f16) m_phi[(k*64+d)*64 + e]
__global__ void k_pre(const float* __restrict__ m_phi, const float* __restrict__ ev,
                      const float* __restrict__ evec, f16* __restrict__ phiT,
                      f16* __restrict__ Apre) {
  int blk = blockIdx.x;
  if (blk < 384) {
    int diag = blk / 24, k = blk % 24;
    float s4 = sqrtf(sqrtf(ev[k]));
    f16* plane = Apre + (size_t)(diag * 24 + k) * 16384;
    for (int idx = threadIdx.x; idx < 16384; idx += 256) {
      int t = idx >> 7, s = idx & 127;
      int v = diag * 128 + t - s;
      float val = (v >= 0) ? evec[v * 24 + k] * s4 : 0.0f;
      plane[idx] = (f16)val;
    }
  } else {
    int k = blk - 384;
    for (int idx = threadIdx.x; idx < 4096; idx += 256) {
      int e = idx >> 6, d = idx & 63;
      phiT[k * 4096 + idx] = (f16)m_phi[(k * 64 + d) * 64 + e];
    }
  }
}

// ---- k_w: W2T[b][k][e][s] = sum_d in[b][s][d] * m_phi[k*64+d][e]   (f16 out)
// grid (16 s-tiles, 16 b, 6 k-groups of 4). [unchanged from R8]
__global__ __launch_bounds__(256) void k_w(const float* __restrict__ in,
                                           const f16* __restrict__ phiT,
                                           f16* __restrict__ W2T) {
  __shared__ __align__(16) f16 Ubuf[8320];
  __shared__ __align__(16) f16 Psm[64 * 64];
  int s0 = blockIdx.x * 128;
  int b = blockIdx.y;
  int kg = blockIdx.z;
  int tid = threadIdx.x, lane = tid & 63, wv = tid >> 6;
#pragma unroll
  for (int v = 0; v < 4; ++v) {
    int flat = v * 256 + tid;
    int row = flat >> 3, cl = flat & 7, cg = cl ^ (row & 7);
    const float* g = in + ((size_t)(b * 2048 + s0 + row)) * 64 + cg * 8;
    float4 u0 = *(const float4*)g;
    float4 u1 = *(const float4*)(g + 4);
    f16x8 h;
    h[0] = (f16)u0.x; h[1] = (f16)u0.y; h[2] = (f16)u0.z; h[3] = (f16)u0.w;
    h[4] = (f16)u1.x; h[5] = (f16)u1.y; h[6] = (f16)u1.z; h[7] = (f16)u1.w;
    *(f16x8*)&Ubuf[row * 64 + cl * 8] = h;
  }
  __syncthreads();
  int wm = wv * 32;
  f16x8 af[2][2];
#pragma unroll
  for (int ks = 0; ks < 2; ++ks)
#pragma unroll
    for (int x = 0; x < 2; ++x) {
      int m = wm + x * 16 + (lane & 15);
      int ch = (ks * 4 + (lane >> 4)) ^ (m & 7);
      af[ks][x] = *(const f16x8*)&Ubuf[m * 64 + ch * 8];
    }
  for (int ki = 0; ki < 4; ++ki) {
    int k = kg * 4 + ki;
#pragma unroll
    for (int v = 0; v < 2; ++v) {
      int flat = v * 256 + tid;
      int row = flat >> 3, cl = flat & 7, cg = cl ^ (row & 7);
      gl_lds16(phiT + (size_t)k * 4096 + row * 64 + cg * 8,
               &Psm[(v * 256 + wv * 64) * 8]);
    }
    __syncthreads();
    f32x4 zero = {0.f, 0.f, 0.f, 0.f};
    f32x4 acc[2][4];
#pragma unroll
    for (int x = 0; x < 2; ++x)
#pragma unroll
      for (int y = 0; y < 4; ++y) acc[x][y] = zero;
#pragma unroll
    for (int ks = 0; ks < 2; ++ks) {
      f16x8 bf[4];
#pragma unroll
      for (int y = 0; y < 4; ++y) {
        int n = y * 16 + (lane & 15);
        int ch = (ks * 4 + (lane >> 4)) ^ (n & 7);
        bf[y] = *(const f16x8*)&Psm[n * 64 + ch * 8];
      }
#pragma unroll
      for (int x = 0; x < 2; ++x)
#pragma unroll
        for (int y = 0; y < 4; ++y)
          acc[x][y] = __builtin_amdgcn_mfma_f32_16x16x32_f16(af[ks][x], bf[y], acc[x][y], 0, 0, 0);
    }
#pragma unroll
    for (int x = 0; x < 2; ++x)
#pragma unroll
      for (int y = 0; y < 4; ++y) {
        int e = y * 16 + (lane & 15);
        int sg = wm + x * 16 + ((lane >> 4) << 2);
        f16x4 pk;
        pk[0] = (f16)acc[x][y][0]; pk[1] = (f16)acc[x][y][1];
        pk[2] = (f16)acc[x][y][2]; pk[3] = (f16)acc[x][y][3];
        *(f16x4*)&Ubuf[e * 130 + sg] = pk;
      }
    __syncthreads();
#pragma unroll
    for (int pass = 0; pass < 4; ++pass) {
      int g = pass * 256 + tid;
      int e = g >> 4, ch = g & 15;
      f16x8 val = *(const f16x8*)&Ubuf[e * 130 + ch * 8];
      *(f16x8*)&W2T[((size_t)((b * 24 + k) * 64 + e)) * 2048 + s0 + ch * 8] = val;
    }
  }
}

// ---- k_main: causal block-Toeplitz GEMM, 128x128 tiles, diag-major grid.
// R9: B stays on the proven R4 gl_lds path; A fragments (16B-contiguous per
// lane) come DIRECTLY from global, but prefetched for iter i+1 BEFORE the
// barrier — the barrier's existing vmcnt(0) drain hides the A latency that
// killed R7. LDS traffic per block-iter: 96KB -> 48KB (writes 32->16, reads
// 64->32). No launch-bounds cap: est ~160 VGPR -> 3 waves/SIMD, no spill.
__global__ __launch_bounds__(256) void k_main(const f16* __restrict__ Apre,
                                              const f16* __restrict__ W2T,
                                              float* __restrict__ out) {
  __shared__ __align__(16) f16 Bsm[128 * 64];  // 16 KB
  int nt = blockIdx.x;
  int q = blockIdx.y;
  int diag = 0, off = 0;
  while (off + (16 - diag) <= q) { off += 16 - diag; ++diag; }
  int st = q - off;
  int mt = st + diag;
  int tid = threadIdx.x, lane = tid & 63, wv = tid >> 6;
  int wm = (wv & 1) * 64, wn = (wv >> 1) * 64;
  int b0 = nt * 2;
  int ml = lane & 15, qv = lane >> 4;

  f32x4 zero = {0.f, 0.f, 0.f, 0.f};
  f32x4 acc[4][4];
#pragma unroll
  for (int x = 0; x < 4; ++x)
#pragma unroll
    for (int y = 0; y < 4; ++y) acc[x][y] = zero;

  const f16* aplane = Apre + (size_t)diag * 24 * 16384;
  // per-lane A row offsets (elements): row (wm+x*16+ml), chunk qv
  int rowoff[4];
#pragma unroll
  for (int x = 0; x < 4; ++x) rowoff[x] = (wm + x * 16 + ml) * 128 + qv * 8;

  // preload A fragments for i=0 (k=0, sh=0)
  f16x8 afc[4][2];
#pragma unroll
  for (int x = 0; x < 4; ++x)
#pragma unroll
    for (int ks = 0; ks < 2; ++ks)
      afc[x][ks] = *(const f16x8*)(aplane + rowoff[x] + ks * 32);

  for (int i = 0; i < 48; ++i) {
    int k = i >> 1;
    int sh = (i & 1) << 6;  // which 64-s half of the s-tile
#pragma unroll
    for (int v = 0; v < 4; ++v) {  // B tile: 128 n-rows x 64 s (16 KB)
      int flat = v * 256 + tid;
      int row = flat >> 3, cl = flat & 7, cg = cl ^ (row & 7);
      int bb = b0 + (row >> 6), e = row & 63;
      gl_lds16(W2T + ((size_t)((bb * 24 + k) * 64 + e)) * 2048 + st * 128 + sh + cg * 8,
               &Bsm[(v * 256 + wv * 64) * 8]);
    }
    // prefetch A for next iter (registers); issued before the barrier so the
    // vmcnt(0) drain we already pay for B staging also covers these loads.
    int inext = (i < 47) ? i + 1 : 47;
    const f16* an = aplane + (size_t)(inext >> 1) * 16384 + ((inext & 1) << 6);
    f16x8 afn[4][2];
#pragma unroll
    for (int x = 0; x < 4; ++x)
#pragma unroll
      for (int ks = 0; ks < 2; ++ks)
        afn[x][ks] = *(const f16x8*)(an + rowoff[x] + ks * 32);
    __syncthreads();
#pragma unroll
    for (int ks = 0; ks < 2; ++ks) {
      f16x8 bf[4];
#pragma unroll
      for (int y = 0; y < 4; ++y) {
        int n = wn + y * 16 + ml;
        int ch = (ks * 4 + qv) ^ (n & 7);
        bf[y] = *(const f16x8*)&Bsm[n * 64 + ch * 8];
      }
#pragma unroll
      for (int x = 0; x < 4; ++x)
#pragma unroll
        for (int y = 0; y < 4; ++y)
          acc[x][y] = __builtin_amdgcn_mfma_f32_16x16x32_f16(afc[x][ks], bf[y], acc[x][y], 0, 0, 0);
    }
#pragma unroll
    for (int x = 0; x < 4; ++x)
#pragma unroll
      for (int ks = 0; ks < 2; ++ks) afc[x][ks] = afn[x][ks];
    __syncthreads();
  }
  int t0 = mt * 128 + wm;
  int n0 = nt * 128 + wn;
#pragma unroll
  for (int x = 0; x < 4; ++x) {
    int rbase = t0 + x * 16 + (qv << 2);
#pragma unroll
    for (int y = 0; y < 4; ++y) {
      int col = n0 + y * 16 + ml;
      int b = col >> 6, e = col & 63;
#pragma unroll
      for (int r = 0; r < 4; ++r)
        atomicAdd(&out[((size_t)(b * 2048 + rbase + r)) * 64 + e], acc[x][y][r]);
    }
  }
}

extern "C" void kernel_launch(void* const* d_in, const int* in_sizes, int n_in,
                              void* d_out, int out_size, void* d_ws, size_t ws_size,
                              hipStream_t stream) {
  const float* inputs = (const float*)d_in[0];  // [16,2048,64]
  const float* m_phi = (const float*)d_in[1];   // [1536,64]
  const float* ev = (const float*)d_in[2];      // [24]
  const float* evec = (const float*)d_in[3];    // [2048,24]
  float* out = (float*)d_out;                   // [16,2048,64] fp32
  char* ws = (char*)d_ws;
  // ws layout: Apre 12,582,912 | phiT 196,608 | W2T 100,663,296
  f16* Apre = (f16*)(ws);
  f16* phiT = (f16*)(ws + 12582912);
  f16* W2T = (f16*)(ws + 12779520);

  hipMemsetAsync(out, 0, (size_t)out_size * 4, stream);
  hipLaunchKernelGGL(k_pre, dim3(408), dim3(256), 0, stream, m_phi, ev, evec, phiT, Apre);
  hipLaunchKernelGGL(k_w, dim3(16, 16, 6), dim3(256), 0, stream, inputs, phiT, W2T);
  hipLaunchKernelGGL(k_main, dim3(8, 136), dim3(256), 0, stream, Apre, W2T, out);
}

// Round 10
// 264.980 us; speedup vs baseline: 1.5911x; 1.5911x over previous
//
#include <hip/hip_runtime.h>

// B=16, L=2048, K=24, D=64
typedef _Float16 f16;
typedef _Float16 f16x4 __attribute__((ext_vector_type(4)));
typedef _Float16 f16x8 __attribute__((ext_vector_type(8)));
typedef float f32x4 __attribute__((ext_vector_type(4)));

__device__ __forceinline__ void gl_lds16(const void* g, void* l) {
  __builtin_amdgcn_global_load_lds(
      (__attribute__((address_space(1))) unsigned int*)(g),
      (__attribute__((address_space(3))) unsigned int*)(l), 16, 0, 0);
}

// ---- k_pre: fused precompute.
// blocks 0..383:   Apre[diag][k][t][s] = lam_k^(1/4) * evec[diag*128+t-s][k]
// blocks 384..407: phiT[k][e][d] = (f16) m_phi[(k*64+d)*64 + e]
__global__ void k_pre(const float* __restrict__ m_phi, const float* __restrict__ ev,
                      const float* __restrict__ evec, f16* __restrict__ phiT,
                      f16* __restrict__ Apre) {
  int blk = blockIdx.x;
  if (blk < 384) {
    int diag = blk / 24, k = blk % 24;
    float s4 = sqrtf(sqrtf(ev[k]));
    f16* plane = Apre + (size_t)(diag * 24 + k) * 16384;
    for (int idx = threadIdx.x; idx < 16384; idx += 256) {
      int t = idx >> 7, s = idx & 127;
      int v = diag * 128 + t - s;
      float val = (v >= 0) ? evec[v * 24 + k] * s4 : 0.0f;
      plane[idx] = (f16)val;
    }
  } else {
    int k = blk - 384;
    for (int idx = threadIdx.x; idx < 4096; idx += 256) {
      int e = idx >> 6, d = idx & 63;
      phiT[k * 4096 + idx] = (f16)m_phi[(k * 64 + d) * 64 + e];
    }
  }
}

// ---- k_w: W2T[b][k][e][s] = sum_d in[b][s][d] * m_phi[k*64+d][e]   (f16 out)
// R10: BARRIER-FREE inner loop. Stage U (16KB) + all 4 phiT k-slices (32KB)
// up front, ONE __syncthreads, then 4 k-iters of MFMA + direct stores.
// No inner barrier -> no vmcnt(0) drain of the previous iter's 16KB of
// stores (the R4-R8 k_w bottleneck theory). LDS 48KB -> 3 blocks/CU.
__global__ __launch_bounds__(256) void k_w(const float* __restrict__ in,
                                           const f16* __restrict__ phiT,
                                           f16* __restrict__ W2T) {
  __shared__ __align__(16) f16 Ubuf[128 * 64];   // 16 KB
  __shared__ __align__(16) f16 Psm[4 * 64 * 64];  // 32 KB (4 k-slices)
  int s0 = blockIdx.x * 128;
  int b = blockIdx.y;
  int kg = blockIdx.z;  // 0..5, covers k = kg*4 .. kg*4+3
  int tid = threadIdx.x, lane = tid & 63, wv = tid >> 6;
  int ml = lane & 15, qv = lane >> 4;
  // stage all 4 P slices via async global->LDS (wave-uniform LDS base).
  // row = flat>>3 in 0..255 = kk*64 + e; swizzle key row&7 == e&7.
#pragma unroll
  for (int v = 0; v < 8; ++v) {
    int flat = v * 256 + tid;
    int row = flat >> 3, cl = flat & 7, cg = cl ^ (row & 7);
    int kk = row >> 6, e = row & 63;
    gl_lds16(phiT + (size_t)(kg * 4 + kk) * 4096 + e * 64 + cg * 8,
             &Psm[(v * 256 + wv * 64) * 8]);
  }
  // stage U: fp32 -> f16, XOR-swizzled 16B chunks
#pragma unroll
  for (int v = 0; v < 4; ++v) {
    int flat = v * 256 + tid;
    int row = flat >> 3, cl = flat & 7, cg = cl ^ (row & 7);
    const float* g = in + ((size_t)(b * 2048 + s0 + row)) * 64 + cg * 8;
    float4 u0 = *(const float4*)g;
    float4 u1 = *(const float4*)(g + 4);
    f16x8 h;
    h[0] = (f16)u0.x; h[1] = (f16)u0.y; h[2] = (f16)u0.z; h[3] = (f16)u0.w;
    h[4] = (f16)u1.x; h[5] = (f16)u1.y; h[6] = (f16)u1.z; h[7] = (f16)u1.w;
    *(f16x8*)&Ubuf[row * 64 + cl * 8] = h;
  }
  __syncthreads();  // the ONLY barrier
  int wm = wv * 32;  // wave's 32 sigma rows
  f16x8 af[2][2];
#pragma unroll
  for (int ks = 0; ks < 2; ++ks)
#pragma unroll
    for (int x = 0; x < 2; ++x) {
      int m = wm + x * 16 + ml;
      int ch = (ks * 4 + qv) ^ (m & 7);
      af[ks][x] = *(const f16x8*)&Ubuf[m * 64 + ch * 8];
    }
#pragma unroll
  for (int ki = 0; ki < 4; ++ki) {
    int k = kg * 4 + ki;
    f32x4 zero = {0.f, 0.f, 0.f, 0.f};
    f32x4 acc[2][4];
#pragma unroll
    for (int x = 0; x < 2; ++x)
#pragma unroll
      for (int y = 0; y < 4; ++y) acc[x][y] = zero;
#pragma unroll
    for (int ks = 0; ks < 2; ++ks) {
      f16x8 bf[4];
#pragma unroll
      for (int y = 0; y < 4; ++y) {
        int n = y * 16 + ml;  // e row
        int ch = (ks * 4 + qv) ^ (n & 7);
        bf[y] = *(const f16x8*)&Psm[ki * 4096 + n * 64 + ch * 8];
      }
#pragma unroll
      for (int x = 0; x < 2; ++x)
#pragma unroll
        for (int y = 0; y < 4; ++y)
          acc[x][y] = __builtin_amdgcn_mfma_f32_16x16x32_f16(af[ks][x], bf[y], acc[x][y], 0, 0, 0);
    }
    // direct stores (proven R1-R3 pattern): reg r = 4 consecutive sigma -> 8B
#pragma unroll
    for (int x = 0; x < 2; ++x)
#pragma unroll
      for (int y = 0; y < 4; ++y) {
        int e = y * 16 + ml;
        int sg = s0 + wm + x * 16 + (qv << 2);
        f16x4 pk;
        pk[0] = (f16)acc[x][y][0]; pk[1] = (f16)acc[x][y][1];
        pk[2] = (f16)acc[x][y][2]; pk[3] = (f16)acc[x][y][3];
        *(f16x4*)&W2T[((size_t)((b * 24 + k) * 64 + e)) * 2048 + sg] = pk;
      }
  }
}

// ---- k_main: causal block-Toeplitz GEMM, 128x128 tiles, split-K over s-tiles
// with fp32 atomicAdd epilogue directly into out[b][t][e].
// grid = (nt 0..7, q 0..135) with q DIAG-MAJOR: same-diag blocks adjacent
// (A-plane L2 reuse), same-out-tile blocks spread (atomic contention spread).
// [exact round-4 version — 157us. FINAL: 128x256 (R2), z-split (R3),
//  A-direct-global naive (R7) and prefetched (R9) all regressed 1.15-2.2x.]
__global__ __launch_bounds__(256, 2) void k_main(const f16* __restrict__ Apre,
                                                 const f16* __restrict__ W2T,
                                                 float* __restrict__ out) {
  __shared__ __align__(16) f16 Asm[128 * 64];
  __shared__ __align__(16) f16 Bsm[128 * 64];
  int nt = blockIdx.x;
  int q = blockIdx.y;
  int diag = 0, off = 0;
  while (off + (16 - diag) <= q) { off += 16 - diag; ++diag; }
  int st = q - off;
  int mt = st + diag;
  int tid = threadIdx.x, lane = tid & 63, wv = tid >> 6;
  int wm = (wv & 1) * 64, wn = (wv >> 1) * 64;
  int b0 = nt * 2;

  f32x4 zero = {0.f, 0.f, 0.f, 0.f};
  f32x4 acc[4][4];
#pragma unroll
  for (int x = 0; x < 4; ++x)
#pragma unroll
    for (int y = 0; y < 4; ++y) acc[x][y] = zero;

  const f16* aplane = Apre + (size_t)diag * 24 * 16384;

  for (int i = 0; i < 48; ++i) {
    int k = i >> 1;
    int sh = (i & 1) << 6;  // which 64-s half of the s-tile
    const f16* ak = aplane + k * 16384;
#pragma unroll
    for (int v = 0; v < 4; ++v) {  // A tile: 128 t-rows x 64 s (16 KB)
      int flat = v * 256 + tid;
      int row = flat >> 3, cl = flat & 7, cg = cl ^ (row & 7);
      gl_lds16(ak + row * 128 + sh + cg * 8, &Asm[(v * 256 + wv * 64) * 8]);
    }
#pragma unroll
    for (int v = 0; v < 4; ++v) {  // B tile: 128 n-rows x 64 s (16 KB)
      int flat = v * 256 + tid;
      int row = flat >> 3, cl = flat & 7, cg = cl ^ (row & 7);
      int bb = b0 + (row >> 6), e = row & 63;
      gl_lds16(W2T + ((size_t)((bb * 24 + k) * 64 + e)) * 2048 + st * 128 + sh + cg * 8,
               &Bsm[(v * 256 + wv * 64) * 8]);
    }
    __syncthreads();
#pragma unroll
    for (int ks = 0; ks < 2; ++ks) {
      f16x8 af[4], bf[4];
#pragma unroll
      for (int x = 0; x < 4; ++x) {
        int m = wm + x * 16 + (lane & 15);
        int ch = (ks * 4 + (lane >> 4)) ^ (m & 7);
        af[x] = *(const f16x8*)&Asm[m * 64 + ch * 8];
      }
#pragma unroll
      for (int y = 0; y < 4; ++y) {
        int n = wn + y * 16 + (lane & 15);
        int ch = (ks * 4 + (lane >> 4)) ^ (n & 7);
        bf[y] = *(const f16x8*)&Bsm[n * 64 + ch * 8];
      }
#pragma unroll
      for (int x = 0; x < 4; ++x)
#pragma unroll
        for (int y = 0; y < 4; ++y)
          acc[x][y] = __builtin_amdgcn_mfma_f32_16x16x32_f16(af[x], bf[y], acc[x][y], 0, 0, 0);
    }
    __syncthreads();
  }
  int t0 = mt * 128 + wm;
  int n0 = nt * 128 + wn;
#pragma unroll
  for (int x = 0; x < 4; ++x) {
    int rbase = t0 + x * 16 + ((lane >> 4) << 2);
#pragma unroll
    for (int y = 0; y < 4; ++y) {
      int col = n0 + y * 16 + (lane & 15);
      int b = col >> 6, e = col & 63;
#pragma unroll
      for (int r = 0; r < 4; ++r)
        atomicAdd(&out[((size_t)(b * 2048 + rbase + r)) * 64 + e], acc[x][y][r]);
    }
  }
}

extern "C" void kernel_launch(void* const* d_in, const int* in_sizes, int n_in,
                              void* d_out, int out_size, void* d_ws, size_t ws_size,
                              hipStream_t stream) {
  const float* inputs = (const float*)d_in[0];  // [16,2048,64]
  const float* m_phi = (const float*)d_in[1];   // [1536,64]
  const float* ev = (const float*)d_in[2];      // [24]
  const float* evec = (const float*)d_in[3];    // [2048,24]
  float* out = (float*)d_out;                   // [16,2048,64] fp32
  char* ws = (char*)d_ws;
  // ws layout: Apre 12,582,912 | phiT 196,608 | W2T 100,663,296
  f16* Apre = (f16*)(ws);
  f16* phiT = (f16*)(ws + 12582912);
  f16* W2T = (f16*)(ws + 12779520);

  hipMemsetAsync(out, 0, (size_t)out_size * 4, stream);
  hipLaunchKernelGGL(k_pre, dim3(408), dim3(256), 0, stream, m_phi, ev, evec, phiT, Apre);
  hipLaunchKernelGGL(k_w, dim3(16, 16, 6), dim3(256), 0, stream, inputs, phiT, W2T);
  hipLaunchKernelGGL(k_main, dim3(8, 136), dim3(256), 0, stream, Apre, W2T, out);
}

// Round 12
// 252.492 us; speedup vs baseline: 1.6698x; 1.0495x over previous
//
#include <hip/hip_runtime.h>

// B=16, L=2048, K=24, D=64
typedef _Float16 f16;
typedef _Float16 f16x4 __attribute__((ext_vector_type(4)));
typedef _Float16 f16x8 __attribute__((ext_vector_type(8)));
typedef float f32x4 __attribute__((ext_vector_type(4)));

__device__ __forceinline__ void gl_lds16(const void* g, void* l) {
  __builtin_amdgcn_global_load_lds(
      (__attribute__((address_space(1))) unsigned int*)(g),
      (__attribute__((address_space(3))) unsigned int*)(l), 16, 0, 0);
}

// ---- k_phi: phiT[k][e][d] = (f16) m_phi[(k*64+d)*64 + e]  (24 blocks; must
// complete before k_front's k_w blocks read phiT -> separate tiny launch)
__global__ void k_phi(const float* __restrict__ m_phi, f16* __restrict__ phiT) {
  int k = blockIdx.x;
  for (int idx = threadIdx.x; idx < 4096; idx += 256) {
    int e = idx >> 6, d = idx & 63;
    phiT[k * 4096 + idx] = (f16)m_phi[(k * 64 + d) * 64 + e];
  }
}

// ---- k_front: fused front-end, 1984 blocks.
//   blk 0..1535:    k_w  (R8 version verbatim: 16 s-tiles x 16 b x 6 kg)
//   blk 1536..1919: Apre[diag][k][t][s] = lam_k^(1/4)*evec[diag*128+t-s][k]
//   blk 1920..1983: zero out[] — 2,097,152 floats total = 32768 floats/block
//                   (R11 bug: used 131072 = byte count -> 24MB OOB -> abort)
// Apre and out feed only k_main (next launch) -> no intra-kernel ordering.
__global__ __launch_bounds__(256) void k_front(const float* __restrict__ in,
                                               const f16* __restrict__ phiT,
                                               const float* __restrict__ ev,
                                               const float* __restrict__ evec,
                                               f16* __restrict__ W2T,
                                               f16* __restrict__ Apre,
                                               float* __restrict__ out) {
  __shared__ __align__(16) f16 Ubuf[8320];
  __shared__ __align__(16) f16 Psm[64 * 64];
  int blk = blockIdx.x;
  int tid = threadIdx.x;
  if (blk >= 1920) {  // ---- zero-out blocks: 64 blocks x 32768 floats
    float4* o = (float4*)(out + (size_t)(blk - 1920) * 32768);
    float4 z4 = {0.f, 0.f, 0.f, 0.f};
#pragma unroll
    for (int i = 0; i < 32; ++i) o[i * 256 + tid] = z4;
    return;
  }
  if (blk >= 1536) {  // ---- Apre blocks
    int a = blk - 1536;
    int diag = a / 24, k = a % 24;
    float s4 = sqrtf(sqrtf(ev[k]));
    f16* plane = Apre + (size_t)(diag * 24 + k) * 16384;
    for (int idx = tid; idx < 16384; idx += 256) {
      int t = idx >> 7, s = idx & 127;
      int v = diag * 128 + t - s;
      float val = (v >= 0) ? evec[v * 24 + k] * s4 : 0.0f;
      plane[idx] = (f16)val;
    }
    return;
  }
  // ---- k_w blocks (R8 version): W2T[b][k][e][s] = sum_d in[b][s][d]*phi
  int s0 = (blk & 15) * 128;
  int b = (blk >> 4) & 15;
  int kg = blk >> 8;  // 0..5
  int lane = tid & 63, wv = tid >> 6;
#pragma unroll
  for (int v = 0; v < 4; ++v) {
    int flat = v * 256 + tid;
    int row = flat >> 3, cl = flat & 7, cg = cl ^ (row & 7);
    const float* g = in + ((size_t)(b * 2048 + s0 + row)) * 64 + cg * 8;
    float4 u0 = *(const float4*)g;
    float4 u1 = *(const float4*)(g + 4);
    f16x8 h;
    h[0] = (f16)u0.x; h[1] = (f16)u0.y; h[2] = (f16)u0.z; h[3] = (f16)u0.w;
    h[4] = (f16)u1.x; h[5] = (f16)u1.y; h[6] = (f16)u1.z; h[7] = (f16)u1.w;
    *(f16x8*)&Ubuf[row * 64 + cl * 8] = h;
  }
  __syncthreads();
  int wm = wv * 32;
  f16x8 af[2][2];
#pragma unroll
  for (int ks = 0; ks < 2; ++ks)
#pragma unroll
    for (int x = 0; x < 2; ++x) {
      int m = wm + x * 16 + (lane & 15);
      int ch = (ks * 4 + (lane >> 4)) ^ (m & 7);
      af[ks][x] = *(const f16x8*)&Ubuf[m * 64 + ch * 8];
    }
  for (int ki = 0; ki < 4; ++ki) {
    int k = kg * 4 + ki;
#pragma unroll
    for (int v = 0; v < 2; ++v) {
      int flat = v * 256 + tid;
      int row = flat >> 3, cl = flat & 7, cg = cl ^ (row & 7);
      gl_lds16(phiT + (size_t)k * 4096 + row * 64 + cg * 8,
               &Psm[(v * 256 + wv * 64) * 8]);
    }
    __syncthreads();
    f32x4 zero = {0.f, 0.f, 0.f, 0.f};
    f32x4 acc[2][4];
#pragma unroll
    for (int x = 0; x < 2; ++x)
#pragma unroll
      for (int y = 0; y < 4; ++y) acc[x][y] = zero;
#pragma unroll
    for (int ks = 0; ks < 2; ++ks) {
      f16x8 bf[4];
#pragma unroll
      for (int y = 0; y < 4; ++y) {
        int n = y * 16 + (lane & 15);
        int ch = (ks * 4 + (lane >> 4)) ^ (n & 7);
        bf[y] = *(const f16x8*)&Psm[n * 64 + ch * 8];
      }
#pragma unroll
      for (int x = 0; x < 2; ++x)
#pragma unroll
        for (int y = 0; y < 4; ++y)
          acc[x][y] = __builtin_amdgcn_mfma_f32_16x16x32_f16(af[ks][x], bf[y], acc[x][y], 0, 0, 0);
    }
    // transpose C (128 sigma x 64 e) into Ubuf as Csm[e][sigma], stride 130
#pragma unroll
    for (int x = 0; x < 2; ++x)
#pragma unroll
      for (int y = 0; y < 4; ++y) {
        int e = y * 16 + (lane & 15);
        int sg = wm + x * 16 + ((lane >> 4) << 2);
        f16x4 pk;
        pk[0] = (f16)acc[x][y][0]; pk[1] = (f16)acc[x][y][1];
        pk[2] = (f16)acc[x][y][2]; pk[3] = (f16)acc[x][y][3];
        *(f16x4*)&Ubuf[e * 130 + sg] = pk;
      }
    __syncthreads();
    // coalesced stores: 1024 chunks of 16B; 16 lanes cover 256B of one e-row
#pragma unroll
    for (int pass = 0; pass < 4; ++pass) {
      int g = pass * 256 + tid;
      int e = g >> 4, ch = g & 15;
      f16x8 val = *(const f16x8*)&Ubuf[e * 130 + ch * 8];
      *(f16x8*)&W2T[((size_t)((b * 24 + k) * 64 + e)) * 2048 + s0 + ch * 8] = val;
    }
  }
}

// ---- k_main: causal block-Toeplitz GEMM, 128x128 tiles, split-K over s-tiles
// with fp32 atomicAdd epilogue directly into out[b][t][e].
// grid = (nt 0..7, q 0..135) with q DIAG-MAJOR: same-diag blocks adjacent
// (A-plane L2 reuse), same-out-tile blocks spread (atomic contention spread).
// [exact round-4 version — 157us. FINAL: 128x256 (R2), z-split (R3),
//  A-direct-global naive (R7) and prefetched (R9) all regressed 1.15-2.2x.]
__global__ __launch_bounds__(256, 2) void k_main(const f16* __restrict__ Apre,
                                                 const f16* __restrict__ W2T,
                                                 float* __restrict__ out) {
  __shared__ __align__(16) f16 Asm[128 * 64];
  __shared__ __align__(16) f16 Bsm[128 * 64];
  int nt = blockIdx.x;
  int q = blockIdx.y;
  int diag = 0, off = 0;
  while (off + (16 - diag) <= q) { off += 16 - diag; ++diag; }
  int st = q - off;
  int mt = st + diag;
  int tid = threadIdx.x, lane = tid & 63, wv = tid >> 6;
  int wm = (wv & 1) * 64, wn = (wv >> 1) * 64;
  int b0 = nt * 2;

  f32x4 zero = {0.f, 0.f, 0.f, 0.f};
  f32x4 acc[4][4];
#pragma unroll
  for (int x = 0; x < 4; ++x)
#pragma unroll
    for (int y = 0; y < 4; ++y) acc[x][y] = zero;

  const f16* aplane = Apre + (size_t)diag * 24 * 16384;

  for (int i = 0; i < 48; ++i) {
    int k = i >> 1;
    int sh = (i & 1) << 6;  // which 64-s half of the s-tile
    const f16* ak = aplane + k * 16384;
#pragma unroll
    for (int v = 0; v < 4; ++v) {  // A tile: 128 t-rows x 64 s (16 KB)
      int flat = v * 256 + tid;
      int row = flat >> 3, cl = flat & 7, cg = cl ^ (row & 7);
      gl_lds16(ak + row * 128 + sh + cg * 8, &Asm[(v * 256 + wv * 64) * 8]);
    }
#pragma unroll
    for (int v = 0; v < 4; ++v) {  // B tile: 128 n-rows x 64 s (16 KB)
      int flat = v * 256 + tid;
      int row = flat >> 3, cl = flat & 7, cg = cl ^ (row & 7);
      int bb = b0 + (row >> 6), e = row & 63;
      gl_lds16(W2T + ((size_t)((bb * 24 + k) * 64 + e)) * 2048 + st * 128 + sh + cg * 8,
               &Bsm[(v * 256 + wv * 64) * 8]);
    }
    __syncthreads();
#pragma unroll
    for (int ks = 0; ks < 2; ++ks) {
      f16x8 af[4], bf[4];
#pragma unroll
      for (int x = 0; x < 4; ++x) {
        int m = wm + x * 16 + (lane & 15);
        int ch = (ks * 4 + (lane >> 4)) ^ (m & 7);
        af[x] = *(const f16x8*)&Asm[m * 64 + ch * 8];
      }
#pragma unroll
      for (int y = 0; y < 4; ++y) {
        int n = wn + y * 16 + (lane & 15);
        int ch = (ks * 4 + (lane >> 4)) ^ (n & 7);
        bf[y] = *(const f16x8*)&Bsm[n * 64 + ch * 8];
      }
#pragma unroll
      for (int x = 0; x < 4; ++x)
#pragma unroll
        for (int y = 0; y < 4; ++y)
          acc[x][y] = __builtin_amdgcn_mfma_f32_16x16x32_f16(af[x], bf[y], acc[x][y], 0, 0, 0);
    }
    __syncthreads();
  }
  int t0 = mt * 128 + wm;
  int n0 = nt * 128 + wn;
#pragma unroll
  for (int x = 0; x < 4; ++x) {
    int rbase = t0 + x * 16 + ((lane >> 4) << 2);
#pragma unroll
    for (int y = 0; y < 4; ++y) {
      int col = n0 + y * 16 + (lane & 15);
      int b = col >> 6, e = col & 63;
#pragma unroll
      for (int r = 0; r < 4; ++r)
        atomicAdd(&out[((size_t)(b * 2048 + rbase + r)) * 64 + e], acc[x][y][r]);
    }
  }
}

extern "C" void kernel_launch(void* const* d_in, const int* in_sizes, int n_in,
                              void* d_out, int out_size, void* d_ws, size_t ws_size,
                              hipStream_t stream) {
  const float* inputs = (const float*)d_in[0];  // [16,2048,64]
  const float* m_phi = (const float*)d_in[1];   // [1536,64]
  const float* ev = (const float*)d_in[2];      // [24]
  const float* evec = (const float*)d_in[3];    // [2048,24]
  float* out = (float*)d_out;                   // [16,2048,64] fp32
  char* ws = (char*)d_ws;
  // ws layout: Apre 12,582,912 | phiT 196,608 | W2T 100,663,296
  f16* Apre = (f16*)(ws);
  f16* phiT = (f16*)(ws + 12582912);
  f16* W2T = (f16*)(ws + 12779520);

  hipLaunchKernelGGL(k_phi, dim3(24), dim3(256), 0, stream, m_phi, phiT);
  hipLaunchKernelGGL(k_front, dim3(1984), dim3(256), 0, stream,
                     inputs, phiT, ev, evec, W2T, Apre, out);
  hipLaunchKernelGGL(k_main, dim3(8, 136), dim3(256), 0, stream, Apre, W2T, out);
}

// Round 13
// 239.731 us; speedup vs baseline: 1.7587x; 1.0532x over previous
//
#include <hip/hip_runtime.h>

// B=16, L=2048, K=24, D=64
typedef _Float16 f16;
typedef _Float16 f16x4 __attribute__((ext_vector_type(4)));
typedef _Float16 f16x8 __attribute__((ext_vector_type(8)));
typedef float f32x4 __attribute__((ext_vector_type(4)));

__device__ __forceinline__ void gl_lds16(const void* g, void* l) {
  __builtin_amdgcn_global_load_lds(
      (__attribute__((address_space(1))) unsigned int*)(g),
      (__attribute__((address_space(3))) unsigned int*)(l), 16, 0, 0);
}

// ---- k_phi: phiT[k][e][d] = (f16) m_phi[(k*64+d)*64 + e]  (24 blocks; must
// complete before k_front's k_w blocks read phiT -> separate tiny launch)
__global__ void k_phi(const float* __restrict__ m_phi, f16* __restrict__ phiT) {
  int k = blockIdx.x;
  for (int idx = threadIdx.x; idx < 4096; idx += 256) {
    int e = idx >> 6, d = idx & 63;
    phiT[k * 4096 + idx] = (f16)m_phi[(k * 64 + d) * 64 + e];
  }
}

// ---- k_front: fused front-end, 1984 blocks, SHORT ARMS FIRST so they overlap
// the k_w ramp instead of forming a serial tail (R12 had them last; fusion
// gained ~0 because dispatch order made them a tail anyway).
//   blk 0..63:      zero out[] (2,097,152 floats = 32768/block)
//   blk 64..447:    Apre[diag][k][t][s] = lam_k^(1/4)*evec[diag*128+t-s][k]
//                   via 255-entry LDS gather (plane touches only 255 evec vals;
//                   direct form = 16K scattered 96B-stride loads per block)
//   blk 448..1983:  k_w (R8 version: 16 s-tiles x 16 b x 6 kg)
__global__ __launch_bounds__(256) void k_front(const float* __restrict__ in,
                                               const f16* __restrict__ phiT,
                                               const float* __restrict__ ev,
                                               const float* __restrict__ evec,
                                               f16* __restrict__ W2T,
                                               f16* __restrict__ Apre,
                                               float* __restrict__ out) {
  __shared__ __align__(16) f16 Ubuf[8320];
  __shared__ __align__(16) f16 Psm[64 * 64];
  __shared__ float esm[256];
  int blk = blockIdx.x;
  int tid = threadIdx.x;
  if (blk < 64) {  // ---- zero-out blocks
    float4* o = (float4*)(out + (size_t)blk * 32768);
    float4 z4 = {0.f, 0.f, 0.f, 0.f};
#pragma unroll
    for (int i = 0; i < 32; ++i) o[i * 256 + tid] = z4;
    return;
  }
  if (blk < 448) {  // ---- Apre blocks (384)
    int a = blk - 64;
    int diag = a / 24, k = a % 24;
    float s4 = sqrtf(sqrtf(ev[k]));
    int base = diag * 128 - 127;  // v range [base, base+254]
    if (tid < 255) {
      int v = base + tid;
      esm[tid] = (v >= 0) ? evec[v * 24 + k] * s4 : 0.0f;
    }
    __syncthreads();
    f16* plane = Apre + (size_t)(diag * 24 + k) * 16384;
    for (int idx = tid; idx < 16384; idx += 256) {
      int t = idx >> 7, s = idx & 127;
      plane[idx] = (f16)esm[127 + t - s];
    }
    return;
  }
  // ---- k_w blocks (R8 version): W2T[b][k][e][s] = sum_d in[b][s][d]*phi
  int wblk = blk - 448;
  int s0 = (wblk & 15) * 128;
  int b = (wblk >> 4) & 15;
  int kg = wblk >> 8;  // 0..5
  int lane = tid & 63, wv = tid >> 6;
#pragma unroll
  for (int v = 0; v < 4; ++v) {
    int flat = v * 256 + tid;
    int row = flat >> 3, cl = flat & 7, cg = cl ^ (row & 7);
    const float* g = in + ((size_t)(b * 2048 + s0 + row)) * 64 + cg * 8;
    float4 u0 = *(const float4*)g;
    float4 u1 = *(const float4*)(g + 4);
    f16x8 h;
    h[0] = (f16)u0.x; h[1] = (f16)u0.y; h[2] = (f16)u0.z; h[3] = (f16)u0.w;
    h[4] = (f16)u1.x; h[5] = (f16)u1.y; h[6] = (f16)u1.z; h[7] = (f16)u1.w;
    *(f16x8*)&Ubuf[row * 64 + cl * 8] = h;
  }
  __syncthreads();
  int wm = wv * 32;
  f16x8 af[2][2];
#pragma unroll
  for (int ks = 0; ks < 2; ++ks)
#pragma unroll
    for (int x = 0; x < 2; ++x) {
      int m = wm + x * 16 + (lane & 15);
      int ch = (ks * 4 + (lane >> 4)) ^ (m & 7);
      af[ks][x] = *(const f16x8*)&Ubuf[m * 64 + ch * 8];
    }
  for (int ki = 0; ki < 4; ++ki) {
    int k = kg * 4 + ki;
#pragma unroll
    for (int v = 0; v < 2; ++v) {
      int flat = v * 256 + tid;
      int row = flat >> 3, cl = flat & 7, cg = cl ^ (row & 7);
      gl_lds16(phiT + (size_t)k * 4096 + row * 64 + cg * 8,
               &Psm[(v * 256 + wv * 64) * 8]);
    }
    __syncthreads();
    f32x4 zero = {0.f, 0.f, 0.f, 0.f};
    f32x4 acc[2][4];
#pragma unroll
    for (int x = 0; x < 2; ++x)
#pragma unroll
      for (int y = 0; y < 4; ++y) acc[x][y] = zero;
#pragma unroll
    for (int ks = 0; ks < 2; ++ks) {
      f16x8 bf[4];
#pragma unroll
      for (int y = 0; y < 4; ++y) {
        int n = y * 16 + (lane & 15);
        int ch = (ks * 4 + (lane >> 4)) ^ (n & 7);
        bf[y] = *(const f16x8*)&Psm[n * 64 + ch * 8];
      }
#pragma unroll
      for (int x = 0; x < 2; ++x)
#pragma unroll
        for (int y = 0; y < 4; ++y)
          acc[x][y] = __builtin_amdgcn_mfma_f32_16x16x32_f16(af[ks][x], bf[y], acc[x][y], 0, 0, 0);
    }
    // transpose C (128 sigma x 64 e) into Ubuf as Csm[e][sigma], stride 130
#pragma unroll
    for (int x = 0; x < 2; ++x)
#pragma unroll
      for (int y = 0; y < 4; ++y) {
        int e = y * 16 + (lane & 15);
        int sg = wm + x * 16 + ((lane >> 4) << 2);
        f16x4 pk;
        pk[0] = (f16)acc[x][y][0]; pk[1] = (f16)acc[x][y][1];
        pk[2] = (f16)acc[x][y][2]; pk[3] = (f16)acc[x][y][3];
        *(f16x4*)&Ubuf[e * 130 + sg] = pk;
      }
    __syncthreads();
    // coalesced stores: 1024 chunks of 16B; 16 lanes cover 256B of one e-row
#pragma unroll
    for (int pass = 0; pass < 4; ++pass) {
      int g = pass * 256 + tid;
      int e = g >> 4, ch = g & 15;
      f16x8 val = *(const f16x8*)&Ubuf[e * 130 + ch * 8];
      *(f16x8*)&W2T[((size_t)((b * 24 + k) * 64 + e)) * 2048 + s0 + ch * 8] = val;
    }
  }
}

// ---- k_main: causal block-Toeplitz GEMM, 128x128 tiles, split-K over s-tiles
// with fp32 atomicAdd epilogue directly into out[b][t][e].
// grid = (nt 0..7, q 0..135) with q DIAG-MAJOR: same-diag blocks adjacent
// (A-plane L2 reuse), same-out-tile blocks spread (atomic contention spread).
// [exact round-4 version — 157us. FINAL: 128x256 (R2), z-split (R3),
//  A-direct-global naive (R7) and prefetched (R9) all regressed 1.15-2.2x.]
__global__ __launch_bounds__(256, 2) void k_main(const f16* __restrict__ Apre,
                                                 const f16* __restrict__ W2T,
                                                 float* __restrict__ out) {
  __shared__ __align__(16) f16 Asm[128 * 64];
  __shared__ __align__(16) f16 Bsm[128 * 64];
  int nt = blockIdx.x;
  int q = blockIdx.y;
  int diag = 0, off = 0;
  while (off + (16 - diag) <= q) { off += 16 - diag; ++diag; }
  int st = q - off;
  int mt = st + diag;
  int tid = threadIdx.x, lane = tid & 63, wv = tid >> 6;
  int wm = (wv & 1) * 64, wn = (wv >> 1) * 64;
  int b0 = nt * 2;

  f32x4 zero = {0.f, 0.f, 0.f, 0.f};
  f32x4 acc[4][4];
#pragma unroll
  for (int x = 0; x < 4; ++x)
#pragma unroll
    for (int y = 0; y < 4; ++y) acc[x][y] = zero;

  const f16* aplane = Apre + (size_t)diag * 24 * 16384;

  for (int i = 0; i < 48; ++i) {
    int k = i >> 1;
    int sh = (i & 1) << 6;  // which 64-s half of the s-tile
    const f16* ak = aplane + k * 16384;
#pragma unroll
    for (int v = 0; v < 4; ++v) {  // A tile: 128 t-rows x 64 s (16 KB)
      int flat = v * 256 + tid;
      int row = flat >> 3, cl = flat & 7, cg = cl ^ (row & 7);
      gl_lds16(ak + row * 128 + sh + cg * 8, &Asm[(v * 256 + wv * 64) * 8]);
    }
#pragma unroll
    for (int v = 0; v < 4; ++v) {  // B tile: 128 n-rows x 64 s (16 KB)
      int flat = v * 256 + tid;
      int row = flat >> 3, cl = flat & 7, cg = cl ^ (row & 7);
      int bb = b0 + (row >> 6), e = row & 63;
      gl_lds16(W2T + ((size_t)((bb * 24 + k) * 64 + e)) * 2048 + st * 128 + sh + cg * 8,
               &Bsm[(v * 256 + wv * 64) * 8]);
    }
    __syncthreads();
#pragma unroll
    for (int ks = 0; ks < 2; ++ks) {
      f16x8 af[4], bf[4];
#pragma unroll
      for (int x = 0; x < 4; ++x) {
        int m = wm + x * 16 + (lane & 15);
        int ch = (ks * 4 + (lane >> 4)) ^ (m & 7);
        af[x] = *(const f16x8*)&Asm[m * 64 + ch * 8];
      }
#pragma unroll
      for (int y = 0; y < 4; ++y) {
        int n = wn + y * 16 + (lane & 15);
        int ch = (ks * 4 + (lane >> 4)) ^ (n & 7);
        bf[y] = *(const f16x8*)&Bsm[n * 64 + ch * 8];
      }
#pragma unroll
      for (int x = 0; x < 4; ++x)
#pragma unroll
        for (int y = 0; y < 4; ++y)
          acc[x][y] = __builtin_amdgcn_mfma_f32_16x16x32_f16(af[x], bf[y], acc[x][y], 0, 0, 0);
    }
    __syncthreads();
  }
  int t0 = mt * 128 + wm;
  int n0 = nt * 128 + wn;
#pragma unroll
  for (int x = 0; x < 4; ++x) {
    int rbase = t0 + x * 16 + ((lane >> 4) << 2);
#pragma unroll
    for (int y = 0; y < 4; ++y) {
      int col = n0 + y * 16 + (lane & 15);
      int b = col >> 6, e = col & 63;
#pragma unroll
      for (int r = 0; r < 4; ++r)
        atomicAdd(&out[((size_t)(b * 2048 + rbase + r)) * 64 + e], acc[x][y][r]);
    }
  }
}

extern "C" void kernel_launch(void* const* d_in, const int* in_sizes, int n_in,
                              void* d_out, int out_size, void* d_ws, size_t ws_size,
                              hipStream_t stream) {
  const float* inputs = (const float*)d_in[0];  // [16,2048,64]
  const float* m_phi = (const float*)d_in[1];   // [1536,64]
  const float* ev = (const float*)d_in[2];      // [24]
  const float* evec = (const float*)d_in[3];    // [2048,24]
  float* out = (float*)d_out;                   // [16,2048,64] fp32
  char* ws = (char*)d_ws;
  // ws layout: Apre 12,582,912 | phiT 196,608 | W2T 100,663,296
  f16* Apre = (f16*)(ws);
  f16* phiT = (f16*)(ws + 12582912);
  f16* W2T = (f16*)(ws + 12779520);

  hipLaunchKernelGGL(k_phi, dim3(24), dim3(256), 0, stream, m_phi, phiT);
  hipLaunchKernelGGL(k_front, dim3(1984), dim3(256), 0, stream,
                     inputs, phiT, ev, evec, W2T, Apre, out);
  hipLaunchKernelGGL(k_main, dim3(8, 136), dim3(256), 0, stream, Apre, W2T, out);
}

// Round 14
// 239.522 us; speedup vs baseline: 1.7602x; 1.0009x over previous
//
#include <hip/hip_runtime.h>

// B=16, L=2048, K=24, D=64
typedef _Float16 f16;
typedef _Float16 f16x4 __attribute__((ext_vector_type(4)));
typedef _Float16 f16x8 __attribute__((ext_vector_type(8)));
typedef float f32x4 __attribute__((ext_vector_type(4)));

__device__ __forceinline__ void gl_lds16(const void* g, void* l) {
  __builtin_amdgcn_global_load_lds(
      (__attribute__((address_space(1))) unsigned int*)(g),
      (__attribute__((address_space(3))) unsigned int*)(l), 16, 0, 0);
}

// ---- k_phi: phiT[k][e][d] = (f16) m_phi[(k*64+d)*64 + e]  (24 blocks; must
// complete before k_front's k_w blocks read phiT -> separate tiny launch)
__global__ void k_phi(const float* __restrict__ m_phi, f16* __restrict__ phiT) {
  int k = blockIdx.x;
  for (int idx = threadIdx.x; idx < 4096; idx += 256) {
    int e = idx >> 6, d = idx & 63;
    phiT[k * 4096 + idx] = (f16)m_phi[(k * 64 + d) * 64 + e];
  }
}

// ---- k_front: fused front-end, 1984 blocks, short arms first (R13: overlap
// the k_w ramp; tail-scheduling fix was worth ~6us, Apre LDS-gather ~7us).
//   blk 0..63:      zero out[] (2,097,152 floats = 32768/block)
//   blk 64..447:    Apre via 255-entry LDS gather
//   blk 448..1983:  k_w (R8 version: 16 s-tiles x 16 b x 6 kg)
__global__ __launch_bounds__(256) void k_front(const float* __restrict__ in,
                                               const f16* __restrict__ phiT,
                                               const float* __restrict__ ev,
                                               const float* __restrict__ evec,
                                               f16* __restrict__ W2T,
                                               f16* __restrict__ Apre,
                                               float* __restrict__ out) {
  __shared__ __align__(16) f16 Ubuf[8320];
  __shared__ __align__(16) f16 Psm[64 * 64];
  __shared__ float esm[256];
  int blk = blockIdx.x;
  int tid = threadIdx.x;
  if (blk < 64) {  // ---- zero-out blocks
    float4* o = (float4*)(out + (size_t)blk * 32768);
    float4 z4 = {0.f, 0.f, 0.f, 0.f};
#pragma unroll
    for (int i = 0; i < 32; ++i) o[i * 256 + tid] = z4;
    return;
  }
  if (blk < 448) {  // ---- Apre blocks (384)
    int a = blk - 64;
    int diag = a / 24, k = a % 24;
    float s4 = sqrtf(sqrtf(ev[k]));
    int base = diag * 128 - 127;  // v range [base, base+254]
    if (tid < 255) {
      int v = base + tid;
      esm[tid] = (v >= 0) ? evec[v * 24 + k] * s4 : 0.0f;
    }
    __syncthreads();
    f16* plane = Apre + (size_t)(diag * 24 + k) * 16384;
    for (int idx = tid; idx < 16384; idx += 256) {
      int t = idx >> 7, s = idx & 127;
      plane[idx] = (f16)esm[127 + t - s];
    }
    return;
  }
  // ---- k_w blocks (R8 version): W2T[b][k][e][s] = sum_d in[b][s][d]*phi
  int wblk = blk - 448;
  int s0 = (wblk & 15) * 128;
  int b = (wblk >> 4) & 15;
  int kg = wblk >> 8;  // 0..5
  int lane = tid & 63, wv = tid >> 6;
#pragma unroll
  for (int v = 0; v < 4; ++v) {
    int flat = v * 256 + tid;
    int row = flat >> 3, cl = flat & 7, cg = cl ^ (row & 7);
    const float* g = in + ((size_t)(b * 2048 + s0 + row)) * 64 + cg * 8;
    float4 u0 = *(const float4*)g;
    float4 u1 = *(const float4*)(g + 4);
    f16x8 h;
    h[0] = (f16)u0.x; h[1] = (f16)u0.y; h[2] = (f16)u0.z; h[3] = (f16)u0.w;
    h[4] = (f16)u1.x; h[5] = (f16)u1.y; h[6] = (f16)u1.z; h[7] = (f16)u1.w;
    *(f16x8*)&Ubuf[row * 64 + cl * 8] = h;
  }
  __syncthreads();
  int wm = wv * 32;
  f16x8 af[2][2];
#pragma unroll
  for (int ks = 0; ks < 2; ++ks)
#pragma unroll
    for (int x = 0; x < 2; ++x) {
      int m = wm + x * 16 + (lane & 15);
      int ch = (ks * 4 + (lane >> 4)) ^ (m & 7);
      af[ks][x] = *(const f16x8*)&Ubuf[m * 64 + ch * 8];
    }
  for (int ki = 0; ki < 4; ++ki) {
    int k = kg * 4 + ki;
#pragma unroll
    for (int v = 0; v < 2; ++v) {
      int flat = v * 256 + tid;
      int row = flat >> 3, cl = flat & 7, cg = cl ^ (row & 7);
      gl_lds16(phiT + (size_t)k * 4096 + row * 64 + cg * 8,
               &Psm[(v * 256 + wv * 64) * 8]);
    }
    __syncthreads();
    f32x4 zero = {0.f, 0.f, 0.f, 0.f};
    f32x4 acc[2][4];
#pragma unroll
    for (int x = 0; x < 2; ++x)
#pragma unroll
      for (int y = 0; y < 4; ++y) acc[x][y] = zero;
#pragma unroll
    for (int ks = 0; ks < 2; ++ks) {
      f16x8 bf[4];
#pragma unroll
      for (int y = 0; y < 4; ++y) {
        int n = y * 16 + (lane & 15);
        int ch = (ks * 4 + (lane >> 4)) ^ (n & 7);
        bf[y] = *(const f16x8*)&Psm[n * 64 + ch * 8];
      }
#pragma unroll
      for (int x = 0; x < 2; ++x)
#pragma unroll
        for (int y = 0; y < 4; ++y)
          acc[x][y] = __builtin_amdgcn_mfma_f32_16x16x32_f16(af[ks][x], bf[y], acc[x][y], 0, 0, 0);
    }
    // transpose C (128 sigma x 64 e) into Ubuf as Csm[e][sigma], stride 130
#pragma unroll
    for (int x = 0; x < 2; ++x)
#pragma unroll
      for (int y = 0; y < 4; ++y) {
        int e = y * 16 + (lane & 15);
        int sg = wm + x * 16 + ((lane >> 4) << 2);
        f16x4 pk;
        pk[0] = (f16)acc[x][y][0]; pk[1] = (f16)acc[x][y][1];
        pk[2] = (f16)acc[x][y][2]; pk[3] = (f16)acc[x][y][3];
        *(f16x4*)&Ubuf[e * 130 + sg] = pk;
      }
    __syncthreads();
    // coalesced stores: 1024 chunks of 16B; 16 lanes cover 256B of one e-row
#pragma unroll
    for (int pass = 0; pass < 4; ++pass) {
      int g = pass * 256 + tid;
      int e = g >> 4, ch = g & 15;
      f16x8 val = *(const f16x8*)&Ubuf[e * 130 + ch * 8];
      *(f16x8*)&W2T[((size_t)((b * 24 + k) * 64 + e)) * 2048 + s0 + ch * 8] = val;
    }
  }
}

// ---- k_main: causal block-Toeplitz GEMM, 128x128 tiles, split-K over s-tiles
// with fp32 atomicAdd epilogue directly into out[b][t][e].
// grid = (nt 0..7, q 0..135) diag-major.
// R14: ONLY change = __launch_bounds__(256,2) -> (256,3). 128 unified
// regs/wave (64 VGPR + 64 AGPR) and 32KB LDS permit >=3 blocks/CU; measured
// Occupancy was stuck at 28% (~2 blocks). More resident blocks = more
// cross-block overlap of the per-iter barrier drains (m114 mechanism).
// Structure otherwise FINAL (R2/R3/R5/R7/R9 restructures all regressed).
__global__ __launch_bounds__(256, 3) void k_main(const f16* __restrict__ Apre,
                                                 const f16* __restrict__ W2T,
                                                 float* __restrict__ out) {
  __shared__ __align__(16) f16 Asm[128 * 64];
  __shared__ __align__(16) f16 Bsm[128 * 64];
  int nt = blockIdx.x;
  int q = blockIdx.y;
  int diag = 0, off = 0;
  while (off + (16 - diag) <= q) { off += 16 - diag; ++diag; }
  int st = q - off;
  int mt = st + diag;
  int tid = threadIdx.x, lane = tid & 63, wv = tid >> 6;
  int wm = (wv & 1) * 64, wn = (wv >> 1) * 64;
  int b0 = nt * 2;

  f32x4 zero = {0.f, 0.f, 0.f, 0.f};
  f32x4 acc[4][4];
#pragma unroll
  for (int x = 0; x < 4; ++x)
#pragma unroll
    for (int y = 0; y < 4; ++y) acc[x][y] = zero;

  const f16* aplane = Apre + (size_t)diag * 24 * 16384;

  for (int i = 0; i < 48; ++i) {
    int k = i >> 1;
    int sh = (i & 1) << 6;  // which 64-s half of the s-tile
    const f16* ak = aplane + k * 16384;
#pragma unroll
    for (int v = 0; v < 4; ++v) {  // A tile: 128 t-rows x 64 s (16 KB)
      int flat = v * 256 + tid;
      int row = flat >> 3, cl = flat & 7, cg = cl ^ (row & 7);
      gl_lds16(ak + row * 128 + sh + cg * 8, &Asm[(v * 256 + wv * 64) * 8]);
    }
#pragma unroll
    for (int v = 0; v < 4; ++v) {  // B tile: 128 n-rows x 64 s (16 KB)
      int flat = v * 256 + tid;
      int row = flat >> 3, cl = flat & 7, cg = cl ^ (row & 7);
      int bb = b0 + (row >> 6), e = row & 63;
      gl_lds16(W2T + ((size_t)((bb * 24 + k) * 64 + e)) * 2048 + st * 128 + sh + cg * 8,
               &Bsm[(v * 256 + wv * 64) * 8]);
    }
    __syncthreads();
#pragma unroll
    for (int ks = 0; ks < 2; ++ks) {
      f16x8 af[4], bf[4];
#pragma unroll
      for (int x = 0; x < 4; ++x) {
        int m = wm + x * 16 + (lane & 15);
        int ch = (ks * 4 + (lane >> 4)) ^ (m & 7);
        af[x] = *(const f16x8*)&Asm[m * 64 + ch * 8];
      }
#pragma unroll
      for (int y = 0; y < 4; ++y) {
        int n = wn + y * 16 + (lane & 15);
        int ch = (ks * 4 + (lane >> 4)) ^ (n & 7);
        bf[y] = *(const f16x8*)&Bsm[n * 64 + ch * 8];
      }
#pragma unroll
      for (int x = 0; x < 4; ++x)
#pragma unroll
        for (int y = 0; y < 4; ++y)
          acc[x][y] = __builtin_amdgcn_mfma_f32_16x16x32_f16(af[x], bf[y], acc[x][y], 0, 0, 0);
    }
    __syncthreads();
  }
  int t0 = mt * 128 + wm;
  int n0 = nt * 128 + wn;
#pragma unroll
  for (int x = 0; x < 4; ++x) {
    int rbase = t0 + x * 16 + ((lane >> 4) << 2);
#pragma unroll
    for (int y = 0; y < 4; ++y) {
      int col = n0 + y * 16 + (lane & 15);
      int b = col >> 6, e = col & 63;
#pragma unroll
      for (int r = 0; r < 4; ++r)
        atomicAdd(&out[((size_t)(b * 2048 + rbase + r)) * 64 + e], acc[x][y][r]);
    }
  }
}

extern "C" void kernel_launch(void* const* d_in, const int* in_sizes, int n_in,
                              void* d_out, int out_size, void* d_ws, size_t ws_size,
                              hipStream_t stream) {
  const float* inputs = (const float*)d_in[0];  // [16,2048,64]
  const float* m_phi = (const float*)d_in[1];   // [1536,64]
  const float* ev = (const float*)d_in[2];      // [24]
  const float* evec = (const float*)d_in[3];    // [2048,24]
  float* out = (float*)d_out;                   // [16,2048,64] fp32
  char* ws = (char*)d_ws;
  // ws layout: Apre 12,582,912 | phiT 196,608 | W2T 100,663,296
  f16* Apre = (f16*)(ws);
  f16* phiT = (f16*)(ws + 12582912);
  f16* W2T = (f16*)(ws + 12779520);

  hipLaunchKernelGGL(k_phi, dim3(24), dim3(256), 0, stream, m_phi, phiT);
  hipLaunchKernelGGL(k_front, dim3(1984), dim3(256), 0, stream,
                     inputs, phiT, ev, evec, W2T, Apre, out);
  hipLaunchKernelGGL(k_main, dim3(8, 136), dim3(256), 0, stream, Apre, W2T, out);
}

// Round 15
// 217.189 us; speedup vs baseline: 1.9412x; 1.1028x over previous
//
#include <hip/hip_runtime.h>

// B=16, L=2048, K=24, D=64
typedef _Float16 f16;
typedef _Float16 f16x4 __attribute__((ext_vector_type(4)));
typedef _Float16 f16x8 __attribute__((ext_vector_type(8)));
typedef float f32x4 __attribute__((ext_vector_type(4)));

__device__ __forceinline__ void gl_lds16(const void* g, void* l) {
  __builtin_amdgcn_global_load_lds(
      (__attribute__((address_space(1))) unsigned int*)(g),
      (__attribute__((address_space(3))) unsigned int*)(l), 16, 0, 0);
}

// ---- k_phi: phiT[k][e][d] = (f16) m_phi[(k*64+d)*64 + e]  (24 blocks)
__global__ void k_phi(const float* __restrict__ m_phi, f16* __restrict__ phiT) {
  int k = blockIdx.x;
  for (int idx = threadIdx.x; idx < 4096; idx += 256) {
    int e = idx >> 6, d = idx & 63;
    phiT[k * 4096 + idx] = (f16)m_phi[(k * 64 + d) * 64 + e];
  }
}

// ---- k_front: fused front-end, 1984 blocks, short arms first.
//   blk 0..63:    zero out[] (2,097,152 floats = 32768/block)
//   blk 64..447:  Dpre[diag][k] phase-replicated Toeplitz table (384 planes):
//                 D[p][y] = esm[254-p-y] (0 if p+y>254), p<8, y<264, plane
//                 padded to 2560 f16 (5120B) for clean 320-chunk gl_lds staging.
//                 Replaces the full 16K-elem Apre tile (510B of info per k!).
//   blk 448..1983: k_w (R8 version: 16 s-tiles x 16 b x 6 kg)
__global__ __launch_bounds__(256) void k_front(const float* __restrict__ in,
                                               const f16* __restrict__ phiT,
                                               const float* __restrict__ ev,
                                               const float* __restrict__ evec,
                                               f16* __restrict__ W2T,
                                               f16* __restrict__ Dpre,
                                               float* __restrict__ out) {
  __shared__ __align__(16) f16 Ubuf[8320];
  __shared__ __align__(16) f16 Psm[64 * 64];
  __shared__ float esm[256];
  int blk = blockIdx.x;
  int tid = threadIdx.x;
  if (blk < 64) {  // ---- zero-out blocks
    float4* o = (float4*)(out + (size_t)blk * 32768);
    float4 z4 = {0.f, 0.f, 0.f, 0.f};
#pragma unroll
    for (int i = 0; i < 32; ++i) o[i * 256 + tid] = z4;
    return;
  }
  if (blk < 448) {  // ---- Dpre blocks (384)
    int a = blk - 64;
    int diag = a / 24, k = a % 24;
    float s4 = sqrtf(sqrtf(ev[k]));
    int base = diag * 128 - 127;  // esm[j] = val for t-s index j-127
    if (tid < 255) {
      int v = base + tid;
      esm[tid] = (v >= 0) ? evec[v * 24 + k] * s4 : 0.0f;
    }
    __syncthreads();
    f16* plane = Dpre + (size_t)(diag * 24 + k) * 2560;
    for (int i = tid; i < 2560; i += 256) {
      float val = 0.f;
      if (i < 2112) {
        int p = i / 264, y = i - p * 264;
        int g = 254 - p - y;
        if (g >= 0) val = esm[g];
      }
      plane[i] = (f16)val;
    }
    return;
  }
  // ---- k_w blocks (R8 version): W2T[b][k][e][s] = sum_d in[b][s][d]*phi
  int wblk = blk - 448;
  int s0 = (wblk & 15) * 128;
  int b = (wblk >> 4) & 15;
  int kg = wblk >> 8;  // 0..5
  int lane = tid & 63, wv = tid >> 6;
#pragma unroll
  for (int v = 0; v < 4; ++v) {
    int flat = v * 256 + tid;
    int row = flat >> 3, cl = flat & 7, cg = cl ^ (row & 7);
    const float* g = in + ((size_t)(b * 2048 + s0 + row)) * 64 + cg * 8;
    float4 u0 = *(const float4*)g;
    float4 u1 = *(const float4*)(g + 4);
    f16x8 h;
    h[0] = (f16)u0.x; h[1] = (f16)u0.y; h[2] = (f16)u0.z; h[3] = (f16)u0.w;
    h[4] = (f16)u1.x; h[5] = (f16)u1.y; h[6] = (f16)u1.z; h[7] = (f16)u1.w;
    *(f16x8*)&Ubuf[row * 64 + cl * 8] = h;
  }
  __syncthreads();
  int wm = wv * 32;
  f16x8 af[2][2];
#pragma unroll
  for (int ks = 0; ks < 2; ++ks)
#pragma unroll
    for (int x = 0; x < 2; ++x) {
      int m = wm + x * 16 + (lane & 15);
      int ch = (ks * 4 + (lane >> 4)) ^ (m & 7);
      af[ks][x] = *(const f16x8*)&Ubuf[m * 64 + ch * 8];
    }
  for (int ki = 0; ki < 4; ++ki) {
    int k = kg * 4 + ki;
#pragma unroll
    for (int v = 0; v < 2; ++v) {
      int flat = v * 256 + tid;
      int row = flat >> 3, cl = flat & 7, cg = cl ^ (row & 7);
      gl_lds16(phiT + (size_t)k * 4096 + row * 64 + cg * 8,
               &Psm[(v * 256 + wv * 64) * 8]);
    }
    __syncthreads();
    f32x4 zero = {0.f, 0.f, 0.f, 0.f};
    f32x4 acc[2][4];
#pragma unroll
    for (int x = 0; x < 2; ++x)
#pragma unroll
      for (int y = 0; y < 4; ++y) acc[x][y] = zero;
#pragma unroll
    for (int ks = 0; ks < 2; ++ks) {
      f16x8 bf[4];
#pragma unroll
      for (int y = 0; y < 4; ++y) {
        int n = y * 16 + (lane & 15);
        int ch = (ks * 4 + (lane >> 4)) ^ (n & 7);
        bf[y] = *(const f16x8*)&Psm[n * 64 + ch * 8];
      }
#pragma unroll
      for (int x = 0; x < 2; ++x)
#pragma unroll
        for (int y = 0; y < 4; ++y)
          acc[x][y] = __builtin_amdgcn_mfma_f32_16x16x32_f16(af[ks][x], bf[y], acc[x][y], 0, 0, 0);
    }
#pragma unroll
    for (int x = 0; x < 2; ++x)
#pragma unroll
      for (int y = 0; y < 4; ++y) {
        int e = y * 16 + (lane & 15);
        int sg = wm + x * 16 + ((lane >> 4) << 2);
        f16x4 pk;
        pk[0] = (f16)acc[x][y][0]; pk[1] = (f16)acc[x][y][1];
        pk[2] = (f16)acc[x][y][2]; pk[3] = (f16)acc[x][y][3];
        *(f16x4*)&Ubuf[e * 130 + sg] = pk;
      }
    __syncthreads();
#pragma unroll
    for (int pass = 0; pass < 4; ++pass) {
      int g = pass * 256 + tid;
      int e = g >> 4, ch = g & 15;
      f16x8 val = *(const f16x8*)&Ubuf[e * 130 + ch * 8];
      *(f16x8*)&W2T[((size_t)((b * 24 + k) * 64 + e)) * 2048 + s0 + ch * 8] = val;
    }
  }
}

// ---- k_main: causal block-Toeplitz GEMM, 128x128 tiles, diag-major grid.
// R15: A-operand compressed to the phase-replicated Toeplitz table Dsm (5KB,
// staged 2 gl_lds/k) instead of a 16KB tile; B staged full-k (BK=128, 32KB).
// Per k: ONE barrier pair (24 vs 48) and 37KB staged (vs 64KB). A-fragment =
// ds_read_b128 at Dsm[p*264 + y0], p=(127-m)&7 lane-determined; bank load is
// even (8 aligned slots x 8 lanes = b128 baseline). Keeps the proven 2-barrier
// gl_lds structure — only the staged payload shrinks.
__global__ __launch_bounds__(256, 3) void k_main(const f16* __restrict__ Dpre,
                                                 const f16* __restrict__ W2T,
                                                 float* __restrict__ out) {
  __shared__ __align__(16) f16 Bsm[128 * 128];  // 32 KB
  __shared__ __align__(16) f16 Dsm[2560];       // 5 KB (2112 used + stage pad)
  int nt = blockIdx.x;
  int q = blockIdx.y;
  int diag = 0, off = 0;
  while (off + (16 - diag) <= q) { off += 16 - diag; ++diag; }
  int st = q - off;
  int mt = st + diag;
  int tid = threadIdx.x, lane = tid & 63, wv = tid >> 6;
  int wm = (wv & 1) * 64, wn = (wv >> 1) * 64;
  int b0 = nt * 2;
  int ml = lane & 15, qv = lane >> 4;
  int p264 = (7 - (ml & 7)) * 264;           // phase row in Dsm
  int yb = (ml < 8 ? 120 : 112) - wm;        // y0 = s0 - x*16 + yb

  f32x4 zero = {0.f, 0.f, 0.f, 0.f};
  f32x4 acc[4][4];
#pragma unroll
  for (int x = 0; x < 4; ++x)
#pragma unroll
    for (int y = 0; y < 4; ++y) acc[x][y] = zero;

  const f16* dplane = Dpre + (size_t)(diag * 24) * 2560;

  for (int k = 0; k < 24; ++k) {
    const f16* dk = dplane + k * 2560;
    // stage D table: 320 chunks (256 all-waves + 64 by wave 0; source padded)
    gl_lds16(dk + tid * 8, &Dsm[(wv * 64) * 8]);
    if (wv == 0) gl_lds16(dk + (256 + lane) * 8, &Dsm[2048]);
    // stage B tile: 128 n-rows x 128 s (32 KB), XOR-swizzled 16B chunks
#pragma unroll
    for (int v = 0; v < 8; ++v) {
      int flat = v * 256 + tid;
      int row = flat >> 4, cl = flat & 15, cg = cl ^ (row & 15);
      int bb = b0 + (row >> 6), e = row & 63;
      gl_lds16(W2T + ((size_t)((bb * 24 + k) * 64 + e)) * 2048 + st * 128 + cg * 8,
               &Bsm[(v * 256 + wv * 64) * 8]);
    }
    __syncthreads();
#pragma unroll
    for (int ks = 0; ks < 4; ++ks) {
      int s0q = ks * 32 + qv * 8;
      f16x8 af[4], bf[4];
#pragma unroll
      for (int x = 0; x < 4; ++x)
        af[x] = *(const f16x8*)&Dsm[p264 + s0q - x * 16 + yb];
#pragma unroll
      for (int y = 0; y < 4; ++y) {
        int n = wn + y * 16 + ml;
        int cl = (ks * 4 + qv) ^ (n & 15);
        bf[y] = *(const f16x8*)&Bsm[n * 128 + cl * 8];
      }
#pragma unroll
      for (int x = 0; x < 4; ++x)
#pragma unroll
        for (int y = 0; y < 4; ++y)
          acc[x][y] = __builtin_amdgcn_mfma_f32_16x16x32_f16(af[x], bf[y], acc[x][y], 0, 0, 0);
    }
    __syncthreads();
  }
  int t0 = mt * 128 + wm;
  int n0 = nt * 128 + wn;
#pragma unroll
  for (int x = 0; x < 4; ++x) {
    int rbase = t0 + x * 16 + (qv << 2);
#pragma unroll
    for (int y = 0; y < 4; ++y) {
      int col = n0 + y * 16 + ml;
      int b = col >> 6, e = col & 63;
#pragma unroll
      for (int r = 0; r < 4; ++r)
        atomicAdd(&out[((size_t)(b * 2048 + rbase + r)) * 64 + e], acc[x][y][r]);
    }
  }
}

extern "C" void kernel_launch(void* const* d_in, const int* in_sizes, int n_in,
                              void* d_out, int out_size, void* d_ws, size_t ws_size,
                              hipStream_t stream) {
  const float* inputs = (const float*)d_in[0];  // [16,2048,64]
  const float* m_phi = (const float*)d_in[1];   // [1536,64]
  const float* ev = (const float*)d_in[2];      // [24]
  const float* evec = (const float*)d_in[3];    // [2048,24]
  float* out = (float*)d_out;                   // [16,2048,64] fp32
  char* ws = (char*)d_ws;
  // ws layout: Dpre 1,966,080 | phiT 196,608 | W2T 100,663,296
  f16* Dpre = (f16*)(ws);
  f16* phiT = (f16*)(ws + 1966080);
  f16* W2T = (f16*)(ws + 2162688);

  hipLaunchKernelGGL(k_phi, dim3(24), dim3(256), 0, stream, m_phi, phiT);
  hipLaunchKernelGGL(k_front, dim3(1984), dim3(256), 0, stream,
                     inputs, phiT, ev, evec, W2T, Dpre, out);
  hipLaunchKernelGGL(k_main, dim3(8, 136), dim3(256), 0, stream, Dpre, W2T, out);
}

// Round 16
// 214.749 us; speedup vs baseline: 1.9633x; 1.0114x over previous
//
#include <hip/hip_runtime.h>

// B=16, L=2048, K=24, D=64
typedef _Float16 f16;
typedef _Float16 f16x4 __attribute__((ext_vector_type(4)));
typedef _Float16 f16x8 __attribute__((ext_vector_type(8)));
typedef float f32x4 __attribute__((ext_vector_type(4)));

__device__ __forceinline__ void gl_lds16(const void* g, void* l) {
  __builtin_amdgcn_global_load_lds(
      (__attribute__((address_space(1))) unsigned int*)(g),
      (__attribute__((address_space(3))) unsigned int*)(l), 16, 0, 0);
}

// ---- k_pre0: ALL independent precompute arms in launch #1 (728 blocks) —
// they ride the otherwise-idle machine during what used to be a 24-block
// k_phi dispatch. Arms:
//   blk 0..255:   uin conversion — in[b][s0+row][cg*8..+8] (fp32) -> f16,
//                 PRE-SWIZZLED planes of 8192 so k_w can stage U with
//                 contiguous gl_lds16 (same trick as phiT staging).
//   blk 256..279: phiT[k][e][d] = (f16) m_phi[(k*64+d)*64+e]
//   blk 280..663: Dpre phase-replicated Toeplitz tables (R15)
//   blk 664..727: zero out[]
__global__ __launch_bounds__(256) void k_pre0(const float* __restrict__ in,
                                              const float* __restrict__ m_phi,
                                              const float* __restrict__ ev,
                                              const float* __restrict__ evec,
                                              f16* __restrict__ phiT,
                                              f16* __restrict__ uin,
                                              f16* __restrict__ Dpre,
                                              float* __restrict__ out) {
  __shared__ float esm[256];
  int blk = blockIdx.x;
  int tid = threadIdx.x;
  if (blk < 256) {  // ---- uin conversion (one 128-s x 64-d plane per block)
    int b = blk >> 4, s0 = (blk & 15) * 128;
    f16* up = uin + (size_t)blk * 8192;
#pragma unroll
    for (int v = 0; v < 4; ++v) {
      int flat = v * 256 + tid;
      int row = flat >> 3, cl = flat & 7, cg = cl ^ (row & 7);
      const float* g = in + ((size_t)(b * 2048 + s0 + row)) * 64 + cg * 8;
      float4 u0 = *(const float4*)g;
      float4 u1 = *(const float4*)(g + 4);
      f16x8 h;
      h[0] = (f16)u0.x; h[1] = (f16)u0.y; h[2] = (f16)u0.z; h[3] = (f16)u0.w;
      h[4] = (f16)u1.x; h[5] = (f16)u1.y; h[6] = (f16)u1.z; h[7] = (f16)u1.w;
      *(f16x8*)&up[flat * 8] = h;
    }
    return;
  }
  if (blk < 280) {  // ---- phiT transpose
    int k = blk - 256;
    for (int idx = tid; idx < 4096; idx += 256) {
      int e = idx >> 6, d = idx & 63;
      phiT[k * 4096 + idx] = (f16)m_phi[(k * 64 + d) * 64 + e];
    }
    return;
  }
  if (blk < 664) {  // ---- Dpre blocks (384): D[p][y]=esm[254-p-y], pad 2560
    int a = blk - 280;
    int diag = a / 24, k = a % 24;
    float s4 = sqrtf(sqrtf(ev[k]));
    int base = diag * 128 - 127;
    if (tid < 255) {
      int v = base + tid;
      esm[tid] = (v >= 0) ? evec[v * 24 + k] * s4 : 0.0f;
    }
    __syncthreads();
    f16* plane = Dpre + (size_t)(diag * 24 + k) * 2560;
    for (int i = tid; i < 2560; i += 256) {
      float val = 0.f;
      if (i < 2112) {
        int p = i / 264, y = i - p * 264;
        int g = 254 - p - y;
        if (g >= 0) val = esm[g];
      }
      plane[i] = (f16)val;
    }
    return;
  }
  // ---- zero-out blocks: 64 blocks x 32768 floats
  float4* o = (float4*)(out + (size_t)(blk - 664) * 32768);
  float4 z4 = {0.f, 0.f, 0.f, 0.f};
#pragma unroll
  for (int i = 0; i < 32; ++i) o[i * 256 + tid] = z4;
}

// ---- k_w: W2T[b][k][e][s] = sum_d in[b][s][d] * m_phi[k*64+d][e]  (f16 out)
// PURE k_w launch (1536 blocks, arms moved to k_pre0). U staged via 4
// contiguous gl_lds16 from pre-swizzled uin (no fp32 loads / converts /
// ds_writes in the prologue); P(k0) prefetched into the same vmcnt group.
__global__ __launch_bounds__(256) void k_w(const f16* __restrict__ uin,
                                           const f16* __restrict__ phiT,
                                           f16* __restrict__ W2T) {
  __shared__ __align__(16) f16 Ubuf[8320];
  __shared__ __align__(16) f16 Psm[64 * 64];
  int wblk = blockIdx.x;
  int s0 = (wblk & 15) * 128;
  int b = (wblk >> 4) & 15;
  int kg = wblk >> 8;  // 0..5
  int tid = threadIdx.x, lane = tid & 63, wv = tid >> 6;
  const f16* up = uin + (size_t)(wblk & 255) * 8192;
  // U stage: contiguous gl_lds (uin pre-swizzled by k_pre0)
#pragma unroll
  for (int v = 0; v < 4; ++v)
    gl_lds16(up + (size_t)(v * 256 + tid) * 8, &Ubuf[(v * 256 + wv * 64) * 8]);
  // P(k0) stage in the same vmcnt group
  {
    int k0 = kg * 4;
#pragma unroll
    for (int v = 0; v < 2; ++v) {
      int flat = v * 256 + tid;
      int row = flat >> 3, cl = flat & 7, cg = cl ^ (row & 7);
      gl_lds16(phiT + (size_t)k0 * 4096 + row * 64 + cg * 8,
               &Psm[(v * 256 + wv * 64) * 8]);
    }
  }
  __syncthreads();  // U + P0 resident
  int wm = wv * 32;
  f16x8 af[2][2];
#pragma unroll
  for (int ks = 0; ks < 2; ++ks)
#pragma unroll
    for (int x = 0; x < 2; ++x) {
      int m = wm + x * 16 + (lane & 15);
      int ch = (ks * 4 + (lane >> 4)) ^ (m & 7);
      af[ks][x] = *(const f16x8*)&Ubuf[m * 64 + ch * 8];
    }
  for (int ki = 0; ki < 4; ++ki) {
    int k = kg * 4 + ki;
    f32x4 zero = {0.f, 0.f, 0.f, 0.f};
    f32x4 acc[2][4];
#pragma unroll
    for (int x = 0; x < 2; ++x)
#pragma unroll
      for (int y = 0; y < 4; ++y) acc[x][y] = zero;
#pragma unroll
    for (int ks = 0; ks < 2; ++ks) {
      f16x8 bf[4];
#pragma unroll
      for (int y = 0; y < 4; ++y) {
        int n = y * 16 + (lane & 15);
        int ch = (ks * 4 + (lane >> 4)) ^ (n & 7);
        bf[y] = *(const f16x8*)&Psm[n * 64 + ch * 8];
      }
#pragma unroll
      for (int x = 0; x < 2; ++x)
#pragma unroll
        for (int y = 0; y < 4; ++y)
          acc[x][y] = __builtin_amdgcn_mfma_f32_16x16x32_f16(af[ks][x], bf[y], acc[x][y], 0, 0, 0);
    }
    __syncthreads();  // Psm reads + (iter0) af Ubuf reads done everywhere
    // transpose C (128 sigma x 64 e) into Ubuf as Csm[e][sigma], stride 130
#pragma unroll
    for (int x = 0; x < 2; ++x)
#pragma unroll
      for (int y = 0; y < 4; ++y) {
        int e = y * 16 + (lane & 15);
        int sg = wm + x * 16 + ((lane >> 4) << 2);
        f16x4 pk;
        pk[0] = (f16)acc[x][y][0]; pk[1] = (f16)acc[x][y][1];
        pk[2] = (f16)acc[x][y][2]; pk[3] = (f16)acc[x][y][3];
        *(f16x4*)&Ubuf[e * 130 + sg] = pk;
      }
    if (ki < 3) {  // prefetch next P (Psm safe to overwrite after sync above)
      int kn = k + 1;
#pragma unroll
      for (int v = 0; v < 2; ++v) {
        int flat = v * 256 + tid;
        int row = flat >> 3, cl = flat & 7, cg = cl ^ (row & 7);
        gl_lds16(phiT + (size_t)kn * 4096 + row * 64 + cg * 8,
                 &Psm[(v * 256 + wv * 64) * 8]);
      }
    }
    __syncthreads();  // Csm visible; P(kn) drained (implicit vmcnt(0))
    // coalesced stores: 1024 chunks of 16B; 16 lanes cover 256B of one e-row
#pragma unroll
    for (int pass = 0; pass < 4; ++pass) {
      int g = pass * 256 + tid;
      int e = g >> 4, ch = g & 15;
      f16x8 val = *(const f16x8*)&Ubuf[e * 130 + ch * 8];
      *(f16x8*)&W2T[((size_t)((b * 24 + k) * 64 + e)) * 2048 + s0 + ch * 8] = val;
    }
  }
}

// ---- k_main: causal block-Toeplitz GEMM, 128x128 tiles, diag-major grid.
// [R15 version UNCHANGED — 130us, MfmaUtil 36%. Toeplitz-compressed A (Dsm
// 5KB phase table), B full-k BK=128 (32KB), one barrier pair per k.]
__global__ __launch_bounds__(256, 3) void k_main(const f16* __restrict__ Dpre,
                                                 const f16* __restrict__ W2T,
                                                 float* __restrict__ out) {
  __shared__ __align__(16) f16 Bsm[128 * 128];  // 32 KB
  __shared__ __align__(16) f16 Dsm[2560];       // 5 KB (2112 used + stage pad)
  int nt = blockIdx.x;
  int q = blockIdx.y;
  int diag = 0, off = 0;
  while (off + (16 - diag) <= q) { off += 16 - diag; ++diag; }
  int st = q - off;
  int mt = st + diag;
  int tid = threadIdx.x, lane = tid & 63, wv = tid >> 6;
  int wm = (wv & 1) * 64, wn = (wv >> 1) * 64;
  int b0 = nt * 2;
  int ml = lane & 15, qv = lane >> 4;
  int p264 = (7 - (ml & 7)) * 264;           // phase row in Dsm
  int yb = (ml < 8 ? 120 : 112) - wm;        // y0 = s0 - x*16 + yb

  f32x4 zero = {0.f, 0.f, 0.f, 0.f};
  f32x4 acc[4][4];
#pragma unroll
  for (int x = 0; x < 4; ++x)
#pragma unroll
    for (int y = 0; y < 4; ++y) acc[x][y] = zero;

  const f16* dplane = Dpre + (size_t)(diag * 24) * 2560;

  for (int k = 0; k < 24; ++k) {
    const f16* dk = dplane + k * 2560;
    // stage D table: 320 chunks (256 all-waves + 64 by wave 0; source padded)
    gl_lds16(dk + tid * 8, &Dsm[(wv * 64) * 8]);
    if (wv == 0) gl_lds16(dk + (256 + lane) * 8, &Dsm[2048]);
    // stage B tile: 128 n-rows x 128 s (32 KB), XOR-swizzled 16B chunks
#pragma unroll
    for (int v = 0; v < 8; ++v) {
      int flat = v * 256 + tid;
      int row = flat >> 4, cl = flat & 15, cg = cl ^ (row & 15);
      int bb = b0 + (row >> 6), e = row & 63;
      gl_lds16(W2T + ((size_t)((bb * 24 + k) * 64 + e)) * 2048 + st * 128 + cg * 8,
               &Bsm[(v * 256 + wv * 64) * 8]);
    }
    __syncthreads();
#pragma unroll
    for (int ks = 0; ks < 4; ++ks) {
      int s0q = ks * 32 + qv * 8;
      f16x8 af[4], bf[4];
#pragma unroll
      for (int x = 0; x < 4; ++x)
        af[x] = *(const f16x8*)&Dsm[p264 + s0q - x * 16 + yb];
#pragma unroll
      for (int y = 0; y < 4; ++y) {
        int n = wn + y * 16 + ml;
        int cl = (ks * 4 + qv) ^ (n & 15);
        bf[y] = *(const f16x8*)&Bsm[n * 128 + cl * 8];
      }
#pragma unroll
      for (int x = 0; x < 4; ++x)
#pragma unroll
        for (int y = 0; y < 4; ++y)
          acc[x][y] = __builtin_amdgcn_mfma_f32_16x16x32_f16(af[x], bf[y], acc[x][y], 0, 0, 0);
    }
    __syncthreads();
  }
  int t0 = mt * 128 + wm;
  int n0 = nt * 128 + wn;
#pragma unroll
  for (int x = 0; x < 4; ++x) {
    int rbase = t0 + x * 16 + (qv << 2);
#pragma unroll
    for (int y = 0; y < 4; ++y) {
      int col = n0 + y * 16 + ml;
      int b = col >> 6, e = col & 63;
#pragma unroll
      for (int r = 0; r < 4; ++r)
        atomicAdd(&out[((size_t)(b * 2048 + rbase + r)) * 64 + e], acc[x][y][r]);
    }
  }
}

extern "C" void kernel_launch(void* const* d_in, const int* in_sizes, int n_in,
                              void* d_out, int out_size, void* d_ws, size_t ws_size,
                              hipStream_t stream) {
  const float* inputs = (const float*)d_in[0];  // [16,2048,64]
  const float* m_phi = (const float*)d_in[1];   // [1536,64]
  const float* ev = (const float*)d_in[2];      // [24]
  const float* evec = (const float*)d_in[3];    // [2048,24]
  float* out = (float*)d_out;                   // [16,2048,64] fp32
  char* ws = (char*)d_ws;
  // ws layout: Dpre 1,966,080 | phiT 196,608 | uin 4,194,304 | W2T 100,663,296
  f16* Dpre = (f16*)(ws);
  f16* phiT = (f16*)(ws + 1966080);
  f16* uin = (f16*)(ws + 2162688);
  f16* W2T = (f16*)(ws + 6356992);

  hipLaunchKernelGGL(k_pre0, dim3(728), dim3(256), 0, stream,
                     inputs, m_phi, ev, evec, phiT, uin, Dpre, out);
  hipLaunchKernelGGL(k_w, dim3(1536), dim3(256), 0, stream, uin, phiT, W2T);
  hipLaunchKernelGGL(k_main, dim3(8, 136), dim3(256), 0, stream, Dpre, W2T, out);
}